// Round 1
// baseline (248.211 us; speedup 1.0000x reference)
//
#include <hip/hip_runtime.h>
#include <math.h>

#define BB 8
#define NN 2048
#define WWID 64
#define RNUM 4
#define CTRL 272      // R*W + R + R*3
#define EPSF 1e-8f
#define TI 32
#define TILES 64      // NN/TI

__device__ __forceinline__ float wred_sum(float v){
#pragma unroll
  for (int m=1;m<64;m<<=1) v += __shfl_xor(v,m);
  return v;
}
__device__ __forceinline__ float wred_max(float v){
#pragma unroll
  for (int m=1;m<64;m<<=1) v = fmaxf(v, __shfl_xor(v,m));
  return v;
}
__device__ __forceinline__ float block_sum(float v, float* sc8){
  int tid=threadIdx.x, wid=tid>>6, lane=tid&63;
  v = wred_sum(v);
  __syncthreads();
  if (lane==0) sc8[wid]=v;
  __syncthreads();
  return sc8[0]+sc8[1]+sc8[2]+sc8[3];
}
__device__ __forceinline__ float block_max(float v, float* sc8){
  int tid=threadIdx.x, wid=tid>>6, lane=tid&63;
  v = wred_max(v);
  __syncthreads();
  if (lane==0) sc8[wid]=v;
  __syncthreads();
  return fmaxf(fmaxf(sc8[0],sc8[1]),fmaxf(sc8[2],sc8[3]));
}

// K1: per (b,n) wave: dots[b,r,n], mem_norm[b,n], a[b,r,n]=(1-ww)*prw
__global__ __launch_bounds__(256) void k1_prep(
    const float* __restrict__ mem, const float* __restrict__ ctr,
    const float* __restrict__ ww, const float* __restrict__ prw,
    float* __restrict__ dots, float* __restrict__ mem_norm,
    float* __restrict__ a_arr){
  int wid = threadIdx.x >> 6, lane = threadIdx.x & 63;
  int g = blockIdx.x * 4 + wid;        // wave id == (b,n)
  int b = g >> 11, n = g & (NN-1);
  float m = mem[((size_t)(b*NN + n))*WWID + lane];
  const float* cb = ctr + b*CTRL;
  float s0 = m*m;
  float d0 = m * cb[0*WWID + lane];
  float d1 = m * cb[1*WWID + lane];
  float d2 = m * cb[2*WWID + lane];
  float d3 = m * cb[3*WWID + lane];
#pragma unroll
  for (int k=1;k<64;k<<=1){
    s0 += __shfl_xor(s0,k);
    d0 += __shfl_xor(d0,k);
    d1 += __shfl_xor(d1,k);
    d2 += __shfl_xor(d2,k);
    d3 += __shfl_xor(d3,k);
  }
  if (lane==0){
    mem_norm[b*NN+n] = sqrtf(s0);
    dots[(b*RNUM+0)*NN+n] = d0;
    dots[(b*RNUM+1)*NN+n] = d1;
    dots[(b*RNUM+2)*NN+n] = d2;
    dots[(b*RNUM+3)*NN+n] = d3;
  }
  if (lane < RNUM){
    int r = lane;
    a_arr[(b*RNUM+r)*NN+n] = (1.f - ww[b*NN+n]) * prw[(b*RNUM+r)*NN+n];
  }
}

// K2: per (b,r) block: content softmax + scalars {g0,g1,g2,S,T}
__global__ __launch_bounds__(256) void k2_head(
    const float* __restrict__ ctr, const float* __restrict__ dots,
    const float* __restrict__ mem_norm, const float* __restrict__ ww,
    const float* __restrict__ prec, const float* __restrict__ prw,
    float* __restrict__ content, float* __restrict__ scal){
  __shared__ float sco[NN];
  __shared__ float sc8[8];
  __shared__ float vars[8];
  int tid = threadIdx.x;
  int b = blockIdx.x >> 2, r = blockIdx.x & 3;
  const float* cb = ctr + b*CTRL;
  if (tid < 64){
    float k = cb[r*WWID + tid];
    float kk = wred_sum(k*k);
    if (tid == 0){
      vars[0] = sqrtf(kk);
      float x = cb[RNUM*WWID + r];
      vars[1] = 1.f + (x > 20.f ? x : log1pf(expf(x)));
      float c0 = cb[RNUM*WWID + RNUM + r*3 + 0];
      float c1 = cb[RNUM*WWID + RNUM + r*3 + 1];
      float c2 = cb[RNUM*WWID + RNUM + r*3 + 2];
      float mg = fmaxf(c0, fmaxf(c1, c2));
      float e0 = expf(c0-mg), e1 = expf(c1-mg), e2 = expf(c2-mg);
      float inv = 1.f/(e0+e1+e2);
      vars[2]=e0*inv; vars[3]=e1*inv; vars[4]=e2*inv;
    }
  }
  __syncthreads();
  float knorm = vars[0], beta = vars[1];
  float lmax = -1e30f, lS = 0.f, lT = 0.f;
  for (int n=tid; n<NN; n+=256){
    float sc = dots[(b*RNUM+r)*NN+n] / (knorm*mem_norm[b*NN+n] + EPSF) * beta;
    sco[n] = sc;
    lmax = fmaxf(lmax, sc);
    float pr = prw[(b*RNUM+r)*NN+n];
    lS = fmaf(prec[b*NN+n], pr, lS);
    lT = fmaf(ww[b*NN+n],  pr, lT);
  }
  float mx = block_max(lmax, sc8);
  float S  = block_sum(lS, sc8);
  float T  = block_sum(lT, sc8);
  float lsum = 0.f;
  for (int n=tid; n<NN; n+=256){
    float e = expf(sco[n]-mx);
    sco[n] = e;
    lsum += e;
  }
  float sum = block_sum(lsum, sc8);
  float inv = 1.f/sum;
  for (int n=tid; n<NN; n+=256)
    content[(b*RNUM+r)*NN+n] = sco[n]*inv;
  if (tid == 0){
    float* s = &scal[(b*RNUM+r)*8];
    s[0]=vars[2]; s[1]=vars[3]; s[2]=vars[4]; s[3]=S; s[4]=T;
  }
}

// K3: single streaming pass over prev_links.
// fwd_raw[b,r,i] = sum_j L[i,j]*(a_r[j] - ww_i*prw_r[j])   (wave-exclusive rows)
// part[b,tile,r,j] = sum_{i in tile} L[i,j]*(a_r[i] - ww_j*prw_r[i])
__global__ __launch_bounds__(256) void k3_links(
    const float* __restrict__ L, const float* __restrict__ ww,
    const float* __restrict__ prw, const float* __restrict__ a_arr,
    float* __restrict__ fwd_raw, float* __restrict__ part){
  __shared__ float lrow[TI][16];       // {ww, pad, pad, pad, a0..a3, p0..p3}
  __shared__ float lcol[256*16];
  int tid = threadIdx.x, wid = tid>>6, lane = tid&63;
  int b = blockIdx.x / TILES, tile = blockIdx.x % TILES;
  int i0 = tile*TI;
  if (tid < TI){
    int i = i0 + tid;
    lrow[tid][0] = ww[b*NN + i];
#pragma unroll
    for (int r=0;r<RNUM;r++){
      lrow[tid][4+r] = a_arr[(b*RNUM+r)*NN + i];
      lrow[tid][8+r] = prw[(b*RNUM+r)*NN + i];
    }
  }
  __syncthreads();
  float accf[8][4];
#pragma unroll
  for (int rr=0;rr<8;rr++)
#pragma unroll
    for (int r=0;r<4;r++) accf[rr][r]=0.f;

  for (int c=0;c<8;c++){
    int j0 = c*256 + lane*4;
    float4 a4[4], p4[4];
#pragma unroll
    for (int r=0;r<4;r++){
      a4[r] = *reinterpret_cast<const float4*>(&a_arr[(b*RNUM+r)*NN + j0]);
      p4[r] = *reinterpret_cast<const float4*>(&prw[(b*RNUM+r)*NN + j0]);
    }
    float4 wwj = *reinterpret_cast<const float4*>(&ww[b*NN + j0]);
    float4 cacc[4];
#pragma unroll
    for (int r=0;r<4;r++){ cacc[r].x=0.f; cacc[r].y=0.f; cacc[r].z=0.f; cacc[r].w=0.f; }

#pragma unroll
    for (int rr=0; rr<8; rr++){
      int lr = wid*8 + rr;
      int i  = i0 + lr;
      float wwi = lrow[lr][0];
      float4 ai4 = *reinterpret_cast<const float4*>(&lrow[lr][4]);
      float4 pi4 = *reinterpret_cast<const float4*>(&lrow[lr][8]);
      float4 L4 = *reinterpret_cast<const float4*>(&L[((size_t)(b*NN + i))*NN + j0]);
#pragma unroll
      for (int r=0;r<4;r++){
        float ax = (r==0)?a4[0].x:((r==1)?a4[1].x:((r==2)?a4[2].x:a4[3].x));
        // use direct indexing (unrolled -> static)
        float4 ar = a4[r], pr = p4[r];
        float mx_ = fmaf(-wwi, pr.x, ar.x);
        float my_ = fmaf(-wwi, pr.y, ar.y);
        float mz_ = fmaf(-wwi, pr.z, ar.z);
        float mw_ = fmaf(-wwi, pr.w, ar.w);
        float s = accf[rr][r];
        s = fmaf(L4.x, mx_, s); s = fmaf(L4.y, my_, s);
        s = fmaf(L4.z, mz_, s); s = fmaf(L4.w, mw_, s);
        accf[rr][r] = s;
        float ai = (r==0)?ai4.x:((r==1)?ai4.y:((r==2)?ai4.z:ai4.w));
        float pi = (r==0)?pi4.x:((r==1)?pi4.y:((r==2)?pi4.z:pi4.w));
        float nx_ = fmaf(-wwj.x, pi, ai);
        float ny_ = fmaf(-wwj.y, pi, ai);
        float nz_ = fmaf(-wwj.z, pi, ai);
        float nw_ = fmaf(-wwj.w, pi, ai);
        cacc[r].x = fmaf(L4.x, nx_, cacc[r].x);
        cacc[r].y = fmaf(L4.y, ny_, cacc[r].y);
        cacc[r].z = fmaf(L4.z, nz_, cacc[r].z);
        cacc[r].w = fmaf(L4.w, nw_, cacc[r].w);
        (void)ax;
      }
    }
    __syncthreads();   // previous chunk's lcol reads done before overwrite
#pragma unroll
    for (int r=0;r<4;r++)
      *reinterpret_cast<float4*>(&lcol[tid*16 + r*4]) = cacc[r];
    __syncthreads();
    // combine 4 waves; thread t handles (r = t>>6, lane cols)
    float4 v; v.x=0.f; v.y=0.f; v.z=0.f; v.w=0.f;
#pragma unroll
    for (int w=0;w<4;w++){
      float4 t = *reinterpret_cast<const float4*>(&lcol[(w*64+lane)*16 + wid*4]);
      v.x+=t.x; v.y+=t.y; v.z+=t.z; v.w+=t.w;
    }
    *reinterpret_cast<float4*>(
      &part[((size_t)((b*TILES+tile)*RNUM + wid))*NN + c*256 + lane*4]) = v;
  }
  // reduce row accumulators across the wave, store
#pragma unroll
  for (int rr=0;rr<8;rr++){
#pragma unroll
    for (int r=0;r<4;r++){
      float v = wred_sum(accf[rr][r]);
      if (lane==0) fwd_raw[(b*RNUM+r)*NN + i0 + wid*8 + rr] = v;
    }
  }
}

// K4: reduce column partials over tiles + epilogue -> read_weights
__global__ __launch_bounds__(256) void k4_combine(
    const float* __restrict__ part, const float* __restrict__ fwd_raw,
    const float* __restrict__ content, const float* __restrict__ scal,
    const float* __restrict__ ww, const float* __restrict__ prec,
    const float* __restrict__ prw, const float* __restrict__ L,
    float* __restrict__ rw){
  int b = blockIdx.x >> 5, rem = blockIdx.x & 31;
  int r = rem >> 3, nb = rem & 7;
  int n = nb*256 + threadIdx.x;
  const float* s = &scal[(b*RNUM+r)*8];
  float g0=s[0], g1=s[1], g2=s[2], S=s[3], T=s[4];
  float bsum = 0.f;
  for (int t=0;t<TILES;t++)
    bsum += part[((size_t)((b*TILES+t)*RNUM + r))*NN + n];
  float wwn = ww[b*NN+n], pn = prec[b*NN+n], prn = prw[(b*RNUM+r)*NN+n];
  float Lnn = L[((size_t)(b*NN+n))*NN + n];
  float diag = (fmaf(-2.f*wwn, Lnn, Lnn) + wwn*pn) * prn;  // (1-2ww)*Lnn + ww*p
  float fwd = fwd_raw[(b*RNUM+r)*NN+n] + wwn*S - diag;
  float bwd = bsum + pn*T - diag;
  rw[(b*RNUM+r)*NN+n] = g0*fwd + g1*bwd + g2*content[(b*RNUM+r)*NN+n];
}

// K5: read_vector[b,r,w] = sum_n memory[b,n,w]*rw[b,r,n]
__global__ __launch_bounds__(256) void k5_read(
    const float* __restrict__ mem, const float* __restrict__ rw,
    float* __restrict__ out){
  __shared__ float rwl[4][128];
  int tid = threadIdx.x;
  int b = blockIdx.x >> 4, ch = blockIdx.x & 15;
  int n0 = ch*128;
  for (int idx=tid; idx<512; idx+=256){
    int r = idx >> 7, nn = idx & 127;
    rwl[r][nn] = rw[(b*RNUM+r)*NN + n0 + nn];
  }
  __syncthreads();
  int wid = tid>>6, lane = tid&63;   // wave == r
  float acc = 0.f;
  for (int nn=0; nn<128; nn++)
    acc = fmaf(mem[((size_t)(b*NN + n0 + nn))*WWID + lane], rwl[wid][nn], acc);
  atomicAdd(&out[(b*RNUM+wid)*WWID + lane], acc);
}

extern "C" void kernel_launch(void* const* d_in, const int* in_sizes, int n_in,
                              void* d_out, int out_size, void* d_ws, size_t ws_size,
                              hipStream_t stream){
  const float* mem  = (const float*)d_in[0];
  const float* ctr  = (const float*)d_in[1];
  const float* ww   = (const float*)d_in[2];
  const float* L    = (const float*)d_in[3];
  const float* prec = (const float*)d_in[4];
  const float* prw  = (const float*)d_in[5];
  float* out = (float*)d_out;
  float* w = (float*)d_ws;

  float* dots     = w;                       // B*R*N
  float* mem_norm = dots + BB*RNUM*NN;       // B*N
  float* a_arr    = mem_norm + BB*NN;        // B*R*N
  float* content  = a_arr + BB*RNUM*NN;      // B*R*N
  float* fwd_raw  = content + BB*RNUM*NN;    // B*R*N
  float* scal     = fwd_raw + BB*RNUM*NN;    // 256
  float* rw       = scal + 256;              // B*R*N
  float* part     = rw + BB*RNUM*NN;         // B*TILES*R*N = 4,194,304

  hipMemsetAsync(out, 0, (size_t)BB*RNUM*WWID*sizeof(float), stream);
  k1_prep<<<BB*NN/4, 256, 0, stream>>>(mem, ctr, ww, prw, dots, mem_norm, a_arr);
  k2_head<<<BB*RNUM, 256, 0, stream>>>(ctr, dots, mem_norm, ww, prec, prw, content, scal);
  k3_links<<<BB*TILES, 256, 0, stream>>>(L, ww, prw, a_arr, fwd_raw, part);
  k4_combine<<<BB*RNUM*8, 256, 0, stream>>>(part, fwd_raw, content, scal, ww, prec, prw, L, rw);
  k5_read<<<BB*16, 256, 0, stream>>>(mem, rw, out);
}